// Round 14
// baseline (344.404 us; speedup 1.0000x reference)
//
#include <hip/hip_runtime.h>

#define EPS_BN 1e-5f
#define NEG_SLOPE 0.01f

#define BINSHIFT 9                 // 512 nodes per bin
#define NBINS_LDS 200              // supports N up to 102400
#define BUFCAP 24                  // LDS records per (block,bin)
#define GSTRIDE 16                 // gcur padding: one counter per 64B line

// ---- bf16x2 pack/unpack (RNE) ----
__device__ __forceinline__ uint32_t pack2_bf16(float x, float y) {
    uint32_t ux = __float_as_uint(x);
    uint32_t uy = __float_as_uint(y);
    ux = (ux + 0x7fffu + ((ux >> 16) & 1u)) >> 16;
    uy = (uy + 0x7fffu + ((uy >> 16) & 1u)) >> 16;
    return (uy << 16) | (ux & 0xffffu);
}
__device__ __forceinline__ float bf_lo(uint32_t p) { return __uint_as_float(p << 16); }
__device__ __forceinline__ float bf_hi(uint32_t p) { return __uint_as_float(p & 0xffff0000u); }

// ---- phase A: LDS multisplit; 4 edges/thread/iter; pipelined drain atomics ----
__global__ void __launch_bounds__(256) stage_ms_kernel(
        const int* __restrict__ src, const int* __restrict__ dst,
        int* __restrict__ gcur, int2* __restrict__ staged,
        int cap, int nbins, int E, int chunk) {
    __shared__ int2 bbuf[NBINS_LDS][BUFCAP];
    __shared__ int bcnt[NBINS_LDS];
    __shared__ int gpos[NBINS_LDS];
    for (int i = threadIdx.x; i < nbins; i += 256) bcnt[i] = 0;
    __syncthreads();
    int e0 = blockIdx.x * chunk;
    int e1 = min(e0 + chunk, E);
    for (int base = e0; base < e1; base += 1024) {       // 256 threads x 4 edges
        int e = base + threadIdx.x * 4;
        int s0, s1, s2, s3, d0, d1, d2, d3;
        int ne = 0;
        if (e + 4 <= e1) {
            int4 s4 = *(const int4*)(src + e);
            int4 d4 = *(const int4*)(dst + e);
            s0 = s4.x; s1 = s4.y; s2 = s4.z; s3 = s4.w;
            d0 = d4.x; d1 = d4.y; d2 = d4.z; d3 = d4.w;
            ne = 4;
        } else {
            int k = 0;
            for (; e + k < e1 && k < 4; ++k) {
                int sv = src[e + k], dv = dst[e + k];
                if (k == 0) { s0 = sv; d0 = dv; }
                else if (k == 1) { s1 = sv; d1 = dv; }
                else if (k == 2) { s2 = sv; d2 = dv; }
                else { s3 = sv; d3 = dv; }
            }
            ne = k;
        }
        #pragma unroll
        for (int k = 0; k < 4; ++k) {
            if (k >= ne) break;
            int s = (k == 0) ? s0 : (k == 1) ? s1 : (k == 2) ? s2 : s3;
            int d = (k == 0) ? d0 : (k == 1) ? d1 : (k == 2) ? d2 : d3;
            int bin = d >> BINSHIFT;
            int pos = atomicAdd(&bcnt[bin], 1);
            if (pos < BUFCAP) {
                bbuf[bin][pos] = make_int2(s, d);
            } else {                                     // rare: direct global append
                int gp = atomicAdd(&gcur[bin * GSTRIDE], 1);
                staged[(size_t)bin * cap + gp] = make_int2(s, d);
            }
        }
    }
    __syncthreads();
    // drain phase 1: one bin per THREAD -> all global atomics issue concurrently
    for (int b = threadIdx.x; b < nbins; b += 256) {
        int c = min(bcnt[b], BUFCAP);
        gpos[b] = (c > 0) ? atomicAdd(&gcur[b * GSTRIDE], c) : 0;
    }
    __syncthreads();
    // drain phase 2: cooperative 16-lane copy per bin
    int grp = threadIdx.x >> 4, lane = threadIdx.x & 15;
    for (int b = grp; b < nbins; b += 16) {
        int c = min(bcnt[b], BUFCAP);
        int gp = gpos[b];
        for (int i = lane; i < c; i += 16)
            staged[(size_t)b * cap + gp + i] = bbuf[b][i];
    }
}

// ---- exclusive scan of per-bin counts -> binbase; also zeros out/gcnt ----
__global__ void binscan_kernel(const int* __restrict__ gcur, int* __restrict__ binbase,
                               int nbins, float* __restrict__ out, float* __restrict__ gcnt,
                               int G) {
    __shared__ int s[256];
    int v = (threadIdx.x < nbins) ? gcur[threadIdx.x * GSTRIDE] : 0;
    s[threadIdx.x] = v;
    __syncthreads();
    for (int off = 1; off < 256; off <<= 1) {
        int t = (threadIdx.x >= off) ? s[threadIdx.x - off] : 0;
        __syncthreads();
        s[threadIdx.x] += t;
        __syncthreads();
    }
    if (threadIdx.x < nbins) binbase[threadIdx.x] = s[threadIdx.x] - v;
    for (int i = threadIdx.x; i < G * 32; i += 256) out[i] = 0.f;
    for (int i = threadIdx.x; i < G; i += 256) gcnt[i] = 0.f;
}

// ---- phase B: per-bin CSR fill + rowptr/cnt/dinv/xs; parallel in-bin scan ----
__global__ void __launch_bounds__(256) fill_csr_kernel(
        const int2* __restrict__ staged, const int* __restrict__ binbase,
        const int* __restrict__ gcur, const float* __restrict__ x,
        int cap, int* __restrict__ rowptr, int* __restrict__ cnt,
        float* __restrict__ dinv, float4* __restrict__ xs,
        int* __restrict__ eidx, int N) {
    __shared__ int lcnt[1 << BINSHIFT];
    __shared__ int loff[1 << BINSHIFT];
    __shared__ int ps[256];
    int bin = blockIdx.x;
    int node0 = bin << BINSHIFT;
    int nn = min(1 << BINSHIFT, N - node0);
    int nrec = gcur[bin * GSTRIDE];
    const int2* recs = staged + (size_t)bin * cap;
    for (int i = threadIdx.x; i < (1 << BINSHIFT); i += 256) lcnt[i] = 0;
    __syncthreads();
    for (int t = threadIdx.x; t < nrec; t += 256) atomicAdd(&lcnt[recs[t].y - node0], 1);
    __syncthreads();
    int p0 = lcnt[2 * threadIdx.x], p1 = lcnt[2 * threadIdx.x + 1];
    int pv = p0 + p1;
    ps[threadIdx.x] = pv;
    __syncthreads();
    for (int off = 1; off < 256; off <<= 1) {
        int t = (threadIdx.x >= off) ? ps[threadIdx.x - off] : 0;
        __syncthreads();
        ps[threadIdx.x] += t;
        __syncthreads();
    }
    int base = ps[threadIdx.x] - pv;
    loff[2 * threadIdx.x] = base;
    loff[2 * threadIdx.x + 1] = base + p0;
    __syncthreads();
    int bb = binbase[bin];
    for (int i = threadIdx.x; i < nn; i += 256) {
        int node = node0 + i;
        rowptr[node] = bb + loff[i];
        cnt[node] = lcnt[i];
        float di = rsqrtf((float)(lcnt[i] + 1));         // +1 self-loop
        dinv[node] = di;
        const float* xr = x + (size_t)node * 3;
        xs[node] = make_float4(xr[0] * di, xr[1] * di, xr[2] * di, 0.f);
        lcnt[i] = 0;                                     // reuse as cursor
    }
    __syncthreads();
    for (int t = threadIdx.x; t < nrec; t += 256) {
        int2 r = recs[t];
        int li = r.y - node0;
        int p = atomicAdd(&lcnt[li], 1);
        eidx[bb + loff[li] + p] = r.x;                   // block-private range
    }
}

// ---- fused layer 1: gather xs + (3->64 GEMM) + bias + BN + LeakyReLU ----
__global__ void __launch_bounds__(256) layer1_kernel(
        const float4* __restrict__ xs, const int* __restrict__ rowptr,
        const int* __restrict__ cnt, const int* __restrict__ eidx,
        const float* __restrict__ dinv, const float* __restrict__ W,
        const float* __restrict__ b, const float* __restrict__ gamma,
        const float* __restrict__ beta, const float* __restrict__ rm,
        const float* __restrict__ rv, float* __restrict__ h, int N) {
    __shared__ float sW[3 * 64];
    __shared__ float sScale[64], sShift[64];
    if (threadIdx.x < 3 * 64) sW[threadIdx.x] = W[threadIdx.x];
    if (threadIdx.x < 64) {
        int f = threadIdx.x;
        float sc = rsqrtf(rv[f] + EPS_BN) * gamma[f];
        sScale[f] = sc;
        sShift[f] = (b[f] - rm[f]) * sc + beta[f];
    }
    __syncthreads();
    int node = blockIdx.x * 8 + (int)(threadIdx.x >> 5);
    if (node >= N) return;
    int lane = threadIdx.x & 31;
    int start = rowptr[node], deg = cnt[node];
    float ax = 0.f, ay = 0.f, az = 0.f;
    for (int j = lane; j < deg; j += 32) {
        float4 v = xs[eidx[start + j]];
        ax += v.x; ay += v.y; az += v.z;
    }
    for (int o = 16; o; o >>= 1) {
        ax += __shfl_down(ax, o, 32);
        ay += __shfl_down(ay, o, 32);
        az += __shfl_down(az, o, 32);
    }
    ax = __shfl(ax, 0, 32); ay = __shfl(ay, 0, 32); az = __shfl(az, 0, 32);
    float4 self = xs[node];
    float di = dinv[node];
    float gx = (ax + self.x) * di, gy = (ay + self.y) * di, gz = (az + self.z) * di;
    int f0 = lane * 2, f1 = f0 + 1;
    float a0 = gx * sW[f0] + gy * sW[64 + f0] + gz * sW[128 + f0];
    float a1 = gx * sW[f1] + gy * sW[64 + f1] + gz * sW[128 + f1];
    float y0 = a0 * sScale[f0] + sShift[f0];
    float y1 = a1 * sScale[f1] + sShift[f1];
    float2 o2;
    o2.x = (y0 >= 0.f) ? y0 : NEG_SLOPE * y0;
    o2.y = (y1 >= 0.f) ? y1 : NEG_SLOPE * y1;
    *(float2*)(h + (size_t)node * 64 + f0) = o2;
}

// ---- dense GEMM + dinv row-scale + bf16 pack; 4 nodes/thread.
// Output layout is SLICE-MAJOR: Tp[slice][node][SW], slice = f2/SW (8 slices).
// Pairs with the XCD-sliced gather: slice region (<=1.6MB) fits one XCD's L2.
// #pragma unroll 1: R10/R11 showed full unroll -> ~1 GB scratch spill.
template <int FIN, int FOUT>
__global__ void __launch_bounds__(256, 4) gemm_pack_scale_kernel(
        const float* __restrict__ H, const float* __restrict__ W,
        const float* __restrict__ dinv, uint32_t* __restrict__ Tp, int N) {
    constexpr int TPN = FOUT / 2;          // threads per node-group
    constexpr int SW = TPN / 8;            // slice width (uint32)
    constexpr int NG = 256 / TPN;          // node-groups per block
    constexpr int NPB = NG * 4;            // nodes per block (4 per group)
    __shared__ float sW[FIN * FOUT];
    for (int i = threadIdx.x; i < FIN * FOUT; i += 256) sW[i] = W[i];
    __syncthreads();
    int grp = threadIdx.x / TPN;
    int f2 = threadIdx.x % TPN;
    int slice = f2 / SW, off = f2 % SW;
    uint32_t* Ts = Tp + (size_t)slice * N * SW + off;
    int n0 = blockIdx.x * NPB + grp;
    int n1 = n0 + NG, n2 = n0 + 2 * NG, n3 = n0 + 3 * NG;
    int m0 = min(n0, N - 1), m1 = min(n1, N - 1), m2 = min(n2, N - 1), m3 = min(n3, N - 1);
    const float* h0 = H + (size_t)m0 * FIN;
    const float* h1 = H + (size_t)m1 * FIN;
    const float* h2 = H + (size_t)m2 * FIN;
    const float* h3 = H + (size_t)m3 * FIN;
    const float2* w2 = (const float2*)sW + f2;
    float a00 = 0.f, a01 = 0.f, a10 = 0.f, a11 = 0.f;
    float a20 = 0.f, a21 = 0.f, a30 = 0.f, a31 = 0.f;
    #pragma unroll 1
    for (int k = 0; k < FIN; k += 4) {
        float4 v0 = *(const float4*)(h0 + k);
        float4 v1 = *(const float4*)(h1 + k);
        float4 v2 = *(const float4*)(h2 + k);
        float4 v3 = *(const float4*)(h3 + k);
        float2 w;
        w = w2[(k + 0) * TPN];
        a00 = fmaf(v0.x, w.x, a00); a01 = fmaf(v0.x, w.y, a01);
        a10 = fmaf(v1.x, w.x, a10); a11 = fmaf(v1.x, w.y, a11);
        a20 = fmaf(v2.x, w.x, a20); a21 = fmaf(v2.x, w.y, a21);
        a30 = fmaf(v3.x, w.x, a30); a31 = fmaf(v3.x, w.y, a31);
        w = w2[(k + 1) * TPN];
        a00 = fmaf(v0.y, w.x, a00); a01 = fmaf(v0.y, w.y, a01);
        a10 = fmaf(v1.y, w.x, a10); a11 = fmaf(v1.y, w.y, a11);
        a20 = fmaf(v2.y, w.x, a20); a21 = fmaf(v2.y, w.y, a21);
        a30 = fmaf(v3.y, w.x, a30); a31 = fmaf(v3.y, w.y, a31);
        w = w2[(k + 2) * TPN];
        a00 = fmaf(v0.z, w.x, a00); a01 = fmaf(v0.z, w.y, a01);
        a10 = fmaf(v1.z, w.x, a10); a11 = fmaf(v1.z, w.y, a11);
        a20 = fmaf(v2.z, w.x, a20); a21 = fmaf(v2.z, w.y, a21);
        a30 = fmaf(v3.z, w.x, a30); a31 = fmaf(v3.z, w.y, a31);
        w = w2[(k + 3) * TPN];
        a00 = fmaf(v0.w, w.x, a00); a01 = fmaf(v0.w, w.y, a01);
        a10 = fmaf(v1.w, w.x, a10); a11 = fmaf(v1.w, w.y, a11);
        a20 = fmaf(v2.w, w.x, a20); a21 = fmaf(v2.w, w.y, a21);
        a30 = fmaf(v3.w, w.x, a30); a31 = fmaf(v3.w, w.y, a31);
    }
    if (n0 < N) { float d = dinv[n0]; Ts[(size_t)n0 * SW] = pack2_bf16(a00 * d, a01 * d); }
    if (n1 < N) { float d = dinv[n1]; Ts[(size_t)n1 * SW] = pack2_bf16(a10 * d, a11 * d); }
    if (n2 < N) { float d = dinv[n2]; Ts[(size_t)n2 * SW] = pack2_bf16(a20 * d, a21 * d); }
    if (n3 < N) { float d = dinv[n3]; Ts[(size_t)n3 * SW] = pack2_bf16(a30 * d, a31 * d); }
}

// ---- CSR gather, XCD-sliced: slice = blockIdx%8 (round-robin -> one XCD).
// Each slice reads only its own Tp region (N*SW uint32 <= 1.6MB -> L2-resident).
// 8-way ILP inner loop; + BN + LeakyReLU epilogue.
template <int F>
__global__ void __launch_bounds__(256) gather_fuse_kernel(
        const uint32_t* __restrict__ Tp, const int* __restrict__ rowptr,
        const int* __restrict__ cnt, const int* __restrict__ eidx,
        const float* __restrict__ dinv,
        const float* __restrict__ b, const float* __restrict__ gamma,
        const float* __restrict__ beta, const float* __restrict__ rm,
        const float* __restrict__ rv,
        float* __restrict__ h, int N) {
    constexpr int TPN = F / 2;
    constexpr int SW = TPN / 8;            // slice width (uint32)
    constexpr int NPB = 256 / SW;          // nodes per block
    int slice = blockIdx.x & 7;
    int chunk = blockIdx.x >> 3;
    int node = chunk * NPB + (int)(threadIdx.x / SW);
    if (node >= N) return;
    int fs = threadIdx.x % SW;
    const uint32_t* Ts = Tp + (size_t)slice * N * SW + fs;
    int start = rowptr[node];
    int deg = cnt[node];
    uint32_t tself = Ts[(size_t)node * SW];
    float a0 = bf_lo(tself), a1 = bf_hi(tself);
    float c0 = 0.f, c1 = 0.f;
    const int* ep = eidx + start;
    int j = 0;
    for (; j + 8 <= deg; j += 8) {
        int s0 = ep[j], s1 = ep[j + 1], s2 = ep[j + 2], s3 = ep[j + 3];
        int s4 = ep[j + 4], s5 = ep[j + 5], s6 = ep[j + 6], s7 = ep[j + 7];
        uint32_t t0 = Ts[(size_t)s0 * SW];
        uint32_t t1 = Ts[(size_t)s1 * SW];
        uint32_t t2 = Ts[(size_t)s2 * SW];
        uint32_t t3 = Ts[(size_t)s3 * SW];
        uint32_t t4 = Ts[(size_t)s4 * SW];
        uint32_t t5 = Ts[(size_t)s5 * SW];
        uint32_t t6 = Ts[(size_t)s6 * SW];
        uint32_t t7 = Ts[(size_t)s7 * SW];
        a0 += bf_lo(t0) + bf_lo(t2) + bf_lo(t4) + bf_lo(t6);
        a1 += bf_hi(t0) + bf_hi(t2) + bf_hi(t4) + bf_hi(t6);
        c0 += bf_lo(t1) + bf_lo(t3) + bf_lo(t5) + bf_lo(t7);
        c1 += bf_hi(t1) + bf_hi(t3) + bf_hi(t5) + bf_hi(t7);
    }
    if (j + 4 <= deg) {
        int s0 = ep[j], s1 = ep[j + 1], s2 = ep[j + 2], s3 = ep[j + 3];
        uint32_t t0 = Ts[(size_t)s0 * SW];
        uint32_t t1 = Ts[(size_t)s1 * SW];
        uint32_t t2 = Ts[(size_t)s2 * SW];
        uint32_t t3 = Ts[(size_t)s3 * SW];
        a0 += bf_lo(t0) + bf_lo(t2);
        a1 += bf_hi(t0) + bf_hi(t2);
        c0 += bf_lo(t1) + bf_lo(t3);
        c1 += bf_hi(t1) + bf_hi(t3);
        j += 4;
    }
    for (; j < deg; ++j) {
        uint32_t t0 = Ts[(size_t)ep[j] * SW];
        a0 += bf_lo(t0); a1 += bf_hi(t0);
    }
    float di = dinv[node];
    int f2 = slice * SW + fs;
    int f0 = 2 * f2, f1 = f0 + 1;
    float sc0 = rsqrtf(rv[f0] + EPS_BN) * gamma[f0];
    float sc1 = rsqrtf(rv[f1] + EPS_BN) * gamma[f1];
    float y0 = (a0 + c0) * di * sc0 + (b[f0] - rm[f0]) * sc0 + beta[f0];
    float y1 = (a1 + c1) * di * sc1 + (b[f1] - rm[f1]) * sc1 + beta[f1];
    float2 o;
    o.x = (y0 >= 0.f) ? y0 : NEG_SLOPE * y0;
    o.y = (y1 >= 0.f) ? y1 : NEG_SLOPE * y1;
    *(float2*)(h + (size_t)node * F + f0) = o;
}

// ---- mean pool: batch sorted -> register-accumulate, flush on graph change ----
#define POOL_ROWS 128
__global__ void pool_kernel2(const float* __restrict__ h, const int* __restrict__ batch,
                             float* __restrict__ out, float* __restrict__ gcnt, int N) {
    int f = threadIdx.x & 31;
    int rg = threadIdx.x >> 5;
    int n0 = blockIdx.x * POOL_ROWS;
    float acc = 0.f;
    int cnt = 0, gcur = -1;
    for (int r = rg; r < POOL_ROWS; r += 8) {
        int node = n0 + r;
        if (node >= N) break;
        int g = batch[node];
        if (g != gcur) {
            if (gcur >= 0) {
                atomicAdd(&out[(gcur << 5) + f], acc);
                if (f == 0) atomicAdd(&gcnt[gcur], (float)cnt);
            }
            gcur = g; acc = 0.f; cnt = 0;
        }
        acc += h[(size_t)node * 32 + f];
        cnt++;
    }
    if (gcur >= 0) {
        atomicAdd(&out[(gcur << 5) + f], acc);
        if (f == 0) atomicAdd(&gcnt[gcur], (float)cnt);
    }
}

__global__ void pool_div_kernel(float* __restrict__ out, const float* __restrict__ gcnt, int G) {
    int tid = blockIdx.x * blockDim.x + threadIdx.x;
    if (tid < (G << 5)) out[tid] /= fmaxf(gcnt[tid >> 5], 1.0f);
}

extern "C" void kernel_launch(void* const* d_in, const int* in_sizes, int n_in,
                              void* d_out, int out_size, void* d_ws, size_t ws_size,
                              hipStream_t stream) {
    const float* x   = (const float*)d_in[0];
    const float* W1  = (const float*)d_in[1];
    const float* b1  = (const float*)d_in[2];
    const float* g1  = (const float*)d_in[3];
    const float* be1 = (const float*)d_in[4];
    const float* rm1 = (const float*)d_in[5];
    const float* rv1 = (const float*)d_in[6];
    const float* W2  = (const float*)d_in[7];
    const float* b2  = (const float*)d_in[8];
    const float* g2  = (const float*)d_in[9];
    const float* be2 = (const float*)d_in[10];
    const float* rm2 = (const float*)d_in[11];
    const float* rv2 = (const float*)d_in[12];
    const float* W3  = (const float*)d_in[13];
    const float* b3  = (const float*)d_in[14];
    const float* g3  = (const float*)d_in[15];
    const float* be3 = (const float*)d_in[16];
    const float* rm3 = (const float*)d_in[17];
    const float* rv3 = (const float*)d_in[18];
    const int* ei    = (const int*)d_in[19];
    const int* batch = (const int*)d_in[20];

    const int N = in_sizes[0] / 3;
    const int E = in_sizes[19] / 2;
    const int G = out_size / 32;
    const int* src = ei;
    const int* dst = ei + E;

    const int B = 256;
    const int nbins = (N + (1 << BINSHIFT) - 1) >> BINSHIFT;          // 196 for N=100k
    const int cap = (((E / nbins) * 3) / 2 + 15) & ~15;               // 1.5x mean
    const int STAGE_BLOCKS = 512;
    const int chunk = (((E + STAGE_BLOCKS - 1) / STAGE_BLOCKS) + 3) & ~3;  // 4-aligned

    // workspace layout
    int*      gcur    = (int*)d_ws;                       // 256*GSTRIDE
    int*      binbase = gcur + 256 * GSTRIDE;             // 256
    int*      cnt     = binbase + 256;                    // N
    float*    dinv    = (float*)(cnt + N);                // N
    int*      rowptr  = (int*)(dinv + N);                 // N
    int*      eidx    = rowptr + N;                       // E
    float4*   xs      = (float4*)(((uintptr_t)(eidx + E) + 15) & ~(uintptr_t)15);  // N
    uint32_t* Tp      = (uint32_t*)(xs + N);              // N*32 (slice-major)
    float*    hbuf    = (float*)(Tp + (size_t)N * 32);    // N*64
    float*    gcnt    = hbuf + (size_t)N * 64;            // G
    int2*     staged  = (int2*)hbuf;                      // alias: dead before hbuf written
    float*    out     = (float*)d_out;

    // ---- CSR build: multisplit stage -> bin scan -> per-bin fill ----
    hipMemsetAsync(gcur, 0, 256 * GSTRIDE * 4, stream);
    stage_ms_kernel<<<STAGE_BLOCKS, 256, 0, stream>>>(src, dst, gcur, staged, cap, nbins, E, chunk);
    binscan_kernel<<<1, 256, 0, stream>>>(gcur, binbase, nbins, out, gcnt, G);
    fill_csr_kernel<<<nbins, 256, 0, stream>>>(staged, binbase, gcur, x, cap,
                                               rowptr, cnt, dinv, xs, eidx, N);

    // ---- layer 1 fused: gather + GEMM(3->64) + BN ----
    layer1_kernel<<<(N + 7) / 8, 256, 0, stream>>>(xs, rowptr, cnt, eidx, dinv,
                                                   W1, b1, g1, be1, rm1, rv1, hbuf, N);

    // ---- layer 2 (gather is XCD-sliced: grid = chunks x 8 slices) ----
    gemm_pack_scale_kernel<64, 64><<<(N + 31) / 32, 256, 0, stream>>>(hbuf, W2, dinv, Tp, N);
    {
        int nchunks = (N + 63) / 64;                      // NPB=64 for F=64 (SW=4)
        gather_fuse_kernel<64><<<nchunks * 8, B, 0, stream>>>(
            Tp, rowptr, cnt, eidx, dinv, b2, g2, be2, rm2, rv2, hbuf, N);
    }

    // ---- layer 3 ----
    gemm_pack_scale_kernel<64, 32><<<(N + 63) / 64, 256, 0, stream>>>(hbuf, W3, dinv, Tp, N);
    {
        int nchunks = (N + 127) / 128;                    // NPB=128 for F=32 (SW=2)
        gather_fuse_kernel<32><<<nchunks * 8, B, 0, stream>>>(
            Tp, rowptr, cnt, eidx, dinv, b3, g3, be3, rm3, rv3, hbuf, N);
    }

    // ---- mean pool ----
    pool_kernel2<<<(N + POOL_ROWS - 1) / POOL_ROWS, 256, 0, stream>>>(hbuf, batch, out, gcnt, N);
    pool_div_kernel<<<(G * 32 + B - 1) / B, B, 0, stream>>>(out, gcnt, G);
}

// Round 15
// 282.570 us; speedup vs baseline: 1.2188x; 1.2188x over previous
//
#include <hip/hip_runtime.h>

#define EPS_BN 1e-5f
#define NEG_SLOPE 0.01f

#define BINSHIFT 9                 // 512 nodes per bin
#define NBINS_LDS 200              // supports N up to 102400
#define BUFCAP 24                  // LDS records per (block,bin)
#define GSTRIDE 16                 // gcur padding: one counter per 64B line

// ---- bf16x2 pack/unpack (RNE) ----
__device__ __forceinline__ uint32_t pack2_bf16(float x, float y) {
    uint32_t ux = __float_as_uint(x);
    uint32_t uy = __float_as_uint(y);
    ux = (ux + 0x7fffu + ((ux >> 16) & 1u)) >> 16;
    uy = (uy + 0x7fffu + ((uy >> 16) & 1u)) >> 16;
    return (uy << 16) | (ux & 0xffffu);
}
__device__ __forceinline__ float bf_lo(uint32_t p) { return __uint_as_float(p << 16); }
__device__ __forceinline__ float bf_hi(uint32_t p) { return __uint_as_float(p & 0xffff0000u); }

// ---- phase A: LDS multisplit; 4 edges/thread/iter; pipelined drain atomics ----
__global__ void __launch_bounds__(256) stage_ms_kernel(
        const int* __restrict__ src, const int* __restrict__ dst,
        int* __restrict__ gcur, int2* __restrict__ staged,
        int cap, int nbins, int E, int chunk) {
    __shared__ int2 bbuf[NBINS_LDS][BUFCAP];
    __shared__ int bcnt[NBINS_LDS];
    __shared__ int gpos[NBINS_LDS];
    for (int i = threadIdx.x; i < nbins; i += 256) bcnt[i] = 0;
    __syncthreads();
    int e0 = blockIdx.x * chunk;
    int e1 = min(e0 + chunk, E);
    for (int base = e0; base < e1; base += 1024) {       // 256 threads x 4 edges
        int e = base + threadIdx.x * 4;
        int s0, s1, s2, s3, d0, d1, d2, d3;
        int ne = 0;
        if (e + 4 <= e1) {
            int4 s4 = *(const int4*)(src + e);
            int4 d4 = *(const int4*)(dst + e);
            s0 = s4.x; s1 = s4.y; s2 = s4.z; s3 = s4.w;
            d0 = d4.x; d1 = d4.y; d2 = d4.z; d3 = d4.w;
            ne = 4;
        } else {
            int k = 0;
            for (; e + k < e1 && k < 4; ++k) {
                int sv = src[e + k], dv = dst[e + k];
                if (k == 0) { s0 = sv; d0 = dv; }
                else if (k == 1) { s1 = sv; d1 = dv; }
                else if (k == 2) { s2 = sv; d2 = dv; }
                else { s3 = sv; d3 = dv; }
            }
            ne = k;
        }
        #pragma unroll
        for (int k = 0; k < 4; ++k) {
            if (k >= ne) break;
            int s = (k == 0) ? s0 : (k == 1) ? s1 : (k == 2) ? s2 : s3;
            int d = (k == 0) ? d0 : (k == 1) ? d1 : (k == 2) ? d2 : d3;
            int bin = d >> BINSHIFT;
            int pos = atomicAdd(&bcnt[bin], 1);
            if (pos < BUFCAP) {
                bbuf[bin][pos] = make_int2(s, d);
            } else {                                     // rare: direct global append
                int gp = atomicAdd(&gcur[bin * GSTRIDE], 1);
                staged[(size_t)bin * cap + gp] = make_int2(s, d);
            }
        }
    }
    __syncthreads();
    // drain phase 1: one bin per THREAD -> all global atomics issue concurrently
    for (int b = threadIdx.x; b < nbins; b += 256) {
        int c = min(bcnt[b], BUFCAP);
        gpos[b] = (c > 0) ? atomicAdd(&gcur[b * GSTRIDE], c) : 0;
    }
    __syncthreads();
    // drain phase 2: cooperative 16-lane copy per bin
    int grp = threadIdx.x >> 4, lane = threadIdx.x & 15;
    for (int b = grp; b < nbins; b += 16) {
        int c = min(bcnt[b], BUFCAP);
        int gp = gpos[b];
        for (int i = lane; i < c; i += 16)
            staged[(size_t)b * cap + gp + i] = bbuf[b][i];
    }
}

// ---- exclusive scan of per-bin counts -> binbase; also zeros out/gcnt ----
__global__ void binscan_kernel(const int* __restrict__ gcur, int* __restrict__ binbase,
                               int nbins, float* __restrict__ out, float* __restrict__ gcnt,
                               int G) {
    __shared__ int s[256];
    int v = (threadIdx.x < nbins) ? gcur[threadIdx.x * GSTRIDE] : 0;
    s[threadIdx.x] = v;
    __syncthreads();
    for (int off = 1; off < 256; off <<= 1) {
        int t = (threadIdx.x >= off) ? s[threadIdx.x - off] : 0;
        __syncthreads();
        s[threadIdx.x] += t;
        __syncthreads();
    }
    if (threadIdx.x < nbins) binbase[threadIdx.x] = s[threadIdx.x] - v;
    for (int i = threadIdx.x; i < G * 32; i += 256) out[i] = 0.f;
    for (int i = threadIdx.x; i < G; i += 256) gcnt[i] = 0.f;
}

// ---- phase B: per-bin CSR fill + rowptr/cnt/dinv/xs; parallel in-bin scan ----
__global__ void __launch_bounds__(256) fill_csr_kernel(
        const int2* __restrict__ staged, const int* __restrict__ binbase,
        const int* __restrict__ gcur, const float* __restrict__ x,
        int cap, int* __restrict__ rowptr, int* __restrict__ cnt,
        float* __restrict__ dinv, float4* __restrict__ xs,
        int* __restrict__ eidx, int N) {
    __shared__ int lcnt[1 << BINSHIFT];
    __shared__ int loff[1 << BINSHIFT];
    __shared__ int ps[256];
    int bin = blockIdx.x;
    int node0 = bin << BINSHIFT;
    int nn = min(1 << BINSHIFT, N - node0);
    int nrec = gcur[bin * GSTRIDE];
    const int2* recs = staged + (size_t)bin * cap;
    for (int i = threadIdx.x; i < (1 << BINSHIFT); i += 256) lcnt[i] = 0;
    __syncthreads();
    for (int t = threadIdx.x; t < nrec; t += 256) atomicAdd(&lcnt[recs[t].y - node0], 1);
    __syncthreads();
    int p0 = lcnt[2 * threadIdx.x], p1 = lcnt[2 * threadIdx.x + 1];
    int pv = p0 + p1;
    ps[threadIdx.x] = pv;
    __syncthreads();
    for (int off = 1; off < 256; off <<= 1) {
        int t = (threadIdx.x >= off) ? ps[threadIdx.x - off] : 0;
        __syncthreads();
        ps[threadIdx.x] += t;
        __syncthreads();
    }
    int base = ps[threadIdx.x] - pv;
    loff[2 * threadIdx.x] = base;
    loff[2 * threadIdx.x + 1] = base + p0;
    __syncthreads();
    int bb = binbase[bin];
    for (int i = threadIdx.x; i < nn; i += 256) {
        int node = node0 + i;
        rowptr[node] = bb + loff[i];
        cnt[node] = lcnt[i];
        float di = rsqrtf((float)(lcnt[i] + 1));         // +1 self-loop
        dinv[node] = di;
        const float* xr = x + (size_t)node * 3;
        xs[node] = make_float4(xr[0] * di, xr[1] * di, xr[2] * di, 0.f);
        lcnt[i] = 0;                                     // reuse as cursor
    }
    __syncthreads();
    for (int t = threadIdx.x; t < nrec; t += 256) {
        int2 r = recs[t];
        int li = r.y - node0;
        int p = atomicAdd(&lcnt[li], 1);
        eidx[bb + loff[li] + p] = r.x;                   // block-private range
    }
}

// ---- fused layer 1: gather xs + (3->64 GEMM) + bias + BN + LeakyReLU ----
__global__ void __launch_bounds__(256) layer1_kernel(
        const float4* __restrict__ xs, const int* __restrict__ rowptr,
        const int* __restrict__ cnt, const int* __restrict__ eidx,
        const float* __restrict__ dinv, const float* __restrict__ W,
        const float* __restrict__ b, const float* __restrict__ gamma,
        const float* __restrict__ beta, const float* __restrict__ rm,
        const float* __restrict__ rv, float* __restrict__ h, int N) {
    __shared__ float sW[3 * 64];
    __shared__ float sScale[64], sShift[64];
    if (threadIdx.x < 3 * 64) sW[threadIdx.x] = W[threadIdx.x];
    if (threadIdx.x < 64) {
        int f = threadIdx.x;
        float sc = rsqrtf(rv[f] + EPS_BN) * gamma[f];
        sScale[f] = sc;
        sShift[f] = (b[f] - rm[f]) * sc + beta[f];
    }
    __syncthreads();
    int node = blockIdx.x * 8 + (int)(threadIdx.x >> 5);
    if (node >= N) return;
    int lane = threadIdx.x & 31;
    int start = rowptr[node], deg = cnt[node];
    float ax = 0.f, ay = 0.f, az = 0.f;
    for (int j = lane; j < deg; j += 32) {
        float4 v = xs[eidx[start + j]];
        ax += v.x; ay += v.y; az += v.z;
    }
    for (int o = 16; o; o >>= 1) {
        ax += __shfl_down(ax, o, 32);
        ay += __shfl_down(ay, o, 32);
        az += __shfl_down(az, o, 32);
    }
    ax = __shfl(ax, 0, 32); ay = __shfl(ay, 0, 32); az = __shfl(az, 0, 32);
    float4 self = xs[node];
    float di = dinv[node];
    float gx = (ax + self.x) * di, gy = (ay + self.y) * di, gz = (az + self.z) * di;
    int f0 = lane * 2, f1 = f0 + 1;
    float a0 = gx * sW[f0] + gy * sW[64 + f0] + gz * sW[128 + f0];
    float a1 = gx * sW[f1] + gy * sW[64 + f1] + gz * sW[128 + f1];
    float y0 = a0 * sScale[f0] + sShift[f0];
    float y1 = a1 * sScale[f1] + sShift[f1];
    float2 o2;
    o2.x = (y0 >= 0.f) ? y0 : NEG_SLOPE * y0;
    o2.y = (y1 >= 0.f) ? y1 : NEG_SLOPE * y1;
    *(float2*)(h + (size_t)node * 64 + f0) = o2;
}

// ---- dense GEMM + dinv row-scale + bf16 pack; 4 nodes/thread, row-major Tp.
// #pragma unroll 1: R10/R11 showed full unroll -> ~1 GB scratch spill.
template <int FIN, int FOUT>
__global__ void __launch_bounds__(256, 4) gemm_pack_scale_kernel(
        const float* __restrict__ H, const float* __restrict__ W,
        const float* __restrict__ dinv, uint32_t* __restrict__ Tp, int N) {
    constexpr int TPN = FOUT / 2;          // threads per node-group
    constexpr int NG = 256 / TPN;          // node-groups per block
    constexpr int NPB = NG * 4;            // nodes per block (4 per group)
    __shared__ float sW[FIN * FOUT];
    for (int i = threadIdx.x; i < FIN * FOUT; i += 256) sW[i] = W[i];
    __syncthreads();
    int grp = threadIdx.x / TPN;
    int f2 = threadIdx.x % TPN;
    int n0 = blockIdx.x * NPB + grp;
    int n1 = n0 + NG, n2 = n0 + 2 * NG, n3 = n0 + 3 * NG;
    int m0 = min(n0, N - 1), m1 = min(n1, N - 1), m2 = min(n2, N - 1), m3 = min(n3, N - 1);
    const float* h0 = H + (size_t)m0 * FIN;
    const float* h1 = H + (size_t)m1 * FIN;
    const float* h2 = H + (size_t)m2 * FIN;
    const float* h3 = H + (size_t)m3 * FIN;
    const float2* w2 = (const float2*)sW + f2;
    float a00 = 0.f, a01 = 0.f, a10 = 0.f, a11 = 0.f;
    float a20 = 0.f, a21 = 0.f, a30 = 0.f, a31 = 0.f;
    #pragma unroll 1
    for (int k = 0; k < FIN; k += 4) {
        float4 v0 = *(const float4*)(h0 + k);
        float4 v1 = *(const float4*)(h1 + k);
        float4 v2 = *(const float4*)(h2 + k);
        float4 v3 = *(const float4*)(h3 + k);
        float2 w;
        w = w2[(k + 0) * TPN];
        a00 = fmaf(v0.x, w.x, a00); a01 = fmaf(v0.x, w.y, a01);
        a10 = fmaf(v1.x, w.x, a10); a11 = fmaf(v1.x, w.y, a11);
        a20 = fmaf(v2.x, w.x, a20); a21 = fmaf(v2.x, w.y, a21);
        a30 = fmaf(v3.x, w.x, a30); a31 = fmaf(v3.x, w.y, a31);
        w = w2[(k + 1) * TPN];
        a00 = fmaf(v0.y, w.x, a00); a01 = fmaf(v0.y, w.y, a01);
        a10 = fmaf(v1.y, w.x, a10); a11 = fmaf(v1.y, w.y, a11);
        a20 = fmaf(v2.y, w.x, a20); a21 = fmaf(v2.y, w.y, a21);
        a30 = fmaf(v3.y, w.x, a30); a31 = fmaf(v3.y, w.y, a31);
        w = w2[(k + 2) * TPN];
        a00 = fmaf(v0.z, w.x, a00); a01 = fmaf(v0.z, w.y, a01);
        a10 = fmaf(v1.z, w.x, a10); a11 = fmaf(v1.z, w.y, a11);
        a20 = fmaf(v2.z, w.x, a20); a21 = fmaf(v2.z, w.y, a21);
        a30 = fmaf(v3.z, w.x, a30); a31 = fmaf(v3.z, w.y, a31);
        w = w2[(k + 3) * TPN];
        a00 = fmaf(v0.w, w.x, a00); a01 = fmaf(v0.w, w.y, a01);
        a10 = fmaf(v1.w, w.x, a10); a11 = fmaf(v1.w, w.y, a11);
        a20 = fmaf(v2.w, w.x, a20); a21 = fmaf(v2.w, w.y, a21);
        a30 = fmaf(v3.w, w.x, a30); a31 = fmaf(v3.w, w.y, a31);
    }
    if (n0 < N) { float d = dinv[n0]; Tp[(size_t)n0 * TPN + f2] = pack2_bf16(a00 * d, a01 * d); }
    if (n1 < N) { float d = dinv[n1]; Tp[(size_t)n1 * TPN + f2] = pack2_bf16(a10 * d, a11 * d); }
    if (n2 < N) { float d = dinv[n2]; Tp[(size_t)n2 * TPN + f2] = pack2_bf16(a20 * d, a21 * d); }
    if (n3 < N) { float d = dinv[n3]; Tp[(size_t)n3 * TPN + f2] = pack2_bf16(a30 * d, a31 * d); }
}

// ---- CSR gather + BN + LeakyReLU. uint2 (8B) per thread: half the load
// instructions of R13's uint32 variant at the same total cache-line count
// (R14 lesson: lines-per-wave-instruction is the currency). 8-edge ILP.
template <int F>
__global__ void __launch_bounds__(256) gather_fuse_kernel(
        const uint32_t* __restrict__ Tp, const int* __restrict__ rowptr,
        const int* __restrict__ cnt, const int* __restrict__ eidx,
        const float* __restrict__ dinv,
        const float* __restrict__ b, const float* __restrict__ gamma,
        const float* __restrict__ beta, const float* __restrict__ rm,
        const float* __restrict__ rv,
        float* __restrict__ h, int N) {
    constexpr int TPN2 = F / 4;            // threads per node (uint2 each)
    int tid = blockIdx.x * blockDim.x + threadIdx.x;
    int node = tid / TPN2;
    if (node >= N) return;
    int fq = tid % TPN2;
    const uint2* T2 = (const uint2*)Tp + fq;             // stride TPN2 per node
    int start = rowptr[node];
    int deg = cnt[node];
    uint2 ts = T2[(size_t)node * TPN2];
    float a0 = bf_lo(ts.x), a1 = bf_hi(ts.x), a2 = bf_lo(ts.y), a3 = bf_hi(ts.y);
    float c0 = 0.f, c1 = 0.f, c2 = 0.f, c3 = 0.f;
    const int* ep = eidx + start;
    int j = 0;
    for (; j + 8 <= deg; j += 8) {
        int s0 = ep[j], s1 = ep[j + 1], s2 = ep[j + 2], s3 = ep[j + 3];
        int s4 = ep[j + 4], s5 = ep[j + 5], s6 = ep[j + 6], s7 = ep[j + 7];
        uint2 t0 = T2[(size_t)s0 * TPN2];
        uint2 t1 = T2[(size_t)s1 * TPN2];
        uint2 t2 = T2[(size_t)s2 * TPN2];
        uint2 t3 = T2[(size_t)s3 * TPN2];
        uint2 t4 = T2[(size_t)s4 * TPN2];
        uint2 t5 = T2[(size_t)s5 * TPN2];
        uint2 t6 = T2[(size_t)s6 * TPN2];
        uint2 t7 = T2[(size_t)s7 * TPN2];
        a0 += bf_lo(t0.x) + bf_lo(t2.x) + bf_lo(t4.x) + bf_lo(t6.x);
        a1 += bf_hi(t0.x) + bf_hi(t2.x) + bf_hi(t4.x) + bf_hi(t6.x);
        a2 += bf_lo(t0.y) + bf_lo(t2.y) + bf_lo(t4.y) + bf_lo(t6.y);
        a3 += bf_hi(t0.y) + bf_hi(t2.y) + bf_hi(t4.y) + bf_hi(t6.y);
        c0 += bf_lo(t1.x) + bf_lo(t3.x) + bf_lo(t5.x) + bf_lo(t7.x);
        c1 += bf_hi(t1.x) + bf_hi(t3.x) + bf_hi(t5.x) + bf_hi(t7.x);
        c2 += bf_lo(t1.y) + bf_lo(t3.y) + bf_lo(t5.y) + bf_lo(t7.y);
        c3 += bf_hi(t1.y) + bf_hi(t3.y) + bf_hi(t5.y) + bf_hi(t7.y);
    }
    if (j + 4 <= deg) {
        int s0 = ep[j], s1 = ep[j + 1], s2 = ep[j + 2], s3 = ep[j + 3];
        uint2 t0 = T2[(size_t)s0 * TPN2];
        uint2 t1 = T2[(size_t)s1 * TPN2];
        uint2 t2 = T2[(size_t)s2 * TPN2];
        uint2 t3 = T2[(size_t)s3 * TPN2];
        a0 += bf_lo(t0.x) + bf_lo(t2.x);  a1 += bf_hi(t0.x) + bf_hi(t2.x);
        a2 += bf_lo(t0.y) + bf_lo(t2.y);  a3 += bf_hi(t0.y) + bf_hi(t2.y);
        c0 += bf_lo(t1.x) + bf_lo(t3.x);  c1 += bf_hi(t1.x) + bf_hi(t3.x);
        c2 += bf_lo(t1.y) + bf_lo(t3.y);  c3 += bf_hi(t1.y) + bf_hi(t3.y);
        j += 4;
    }
    for (; j < deg; ++j) {
        uint2 t0 = T2[(size_t)ep[j] * TPN2];
        a0 += bf_lo(t0.x); a1 += bf_hi(t0.x);
        a2 += bf_lo(t0.y); a3 += bf_hi(t0.y);
    }
    float di = dinv[node];
    int f0 = 4 * fq;
    float s0 = rsqrtf(rv[f0 + 0] + EPS_BN) * gamma[f0 + 0];
    float s1 = rsqrtf(rv[f0 + 1] + EPS_BN) * gamma[f0 + 1];
    float s2 = rsqrtf(rv[f0 + 2] + EPS_BN) * gamma[f0 + 2];
    float s3 = rsqrtf(rv[f0 + 3] + EPS_BN) * gamma[f0 + 3];
    float y0 = (a0 + c0) * di * s0 + (b[f0 + 0] - rm[f0 + 0]) * s0 + beta[f0 + 0];
    float y1 = (a1 + c1) * di * s1 + (b[f0 + 1] - rm[f0 + 1]) * s1 + beta[f0 + 1];
    float y2 = (a2 + c2) * di * s2 + (b[f0 + 2] - rm[f0 + 2]) * s2 + beta[f0 + 2];
    float y3 = (a3 + c3) * di * s3 + (b[f0 + 3] - rm[f0 + 3]) * s3 + beta[f0 + 3];
    float4 o;
    o.x = (y0 >= 0.f) ? y0 : NEG_SLOPE * y0;
    o.y = (y1 >= 0.f) ? y1 : NEG_SLOPE * y1;
    o.z = (y2 >= 0.f) ? y2 : NEG_SLOPE * y2;
    o.w = (y3 >= 0.f) ? y3 : NEG_SLOPE * y3;
    *(float4*)(h + (size_t)node * F + f0) = o;
}

// ---- mean pool: batch sorted -> register-accumulate, flush on graph change ----
#define POOL_ROWS 128
__global__ void pool_kernel2(const float* __restrict__ h, const int* __restrict__ batch,
                             float* __restrict__ out, float* __restrict__ gcnt, int N) {
    int f = threadIdx.x & 31;
    int rg = threadIdx.x >> 5;
    int n0 = blockIdx.x * POOL_ROWS;
    float acc = 0.f;
    int cnt = 0, gcur = -1;
    for (int r = rg; r < POOL_ROWS; r += 8) {
        int node = n0 + r;
        if (node >= N) break;
        int g = batch[node];
        if (g != gcur) {
            if (gcur >= 0) {
                atomicAdd(&out[(gcur << 5) + f], acc);
                if (f == 0) atomicAdd(&gcnt[gcur], (float)cnt);
            }
            gcur = g; acc = 0.f; cnt = 0;
        }
        acc += h[(size_t)node * 32 + f];
        cnt++;
    }
    if (gcur >= 0) {
        atomicAdd(&out[(gcur << 5) + f], acc);
        if (f == 0) atomicAdd(&gcnt[gcur], (float)cnt);
    }
}

__global__ void pool_div_kernel(float* __restrict__ out, const float* __restrict__ gcnt, int G) {
    int tid = blockIdx.x * blockDim.x + threadIdx.x;
    if (tid < (G << 5)) out[tid] /= fmaxf(gcnt[tid >> 5], 1.0f);
}

extern "C" void kernel_launch(void* const* d_in, const int* in_sizes, int n_in,
                              void* d_out, int out_size, void* d_ws, size_t ws_size,
                              hipStream_t stream) {
    const float* x   = (const float*)d_in[0];
    const float* W1  = (const float*)d_in[1];
    const float* b1  = (const float*)d_in[2];
    const float* g1  = (const float*)d_in[3];
    const float* be1 = (const float*)d_in[4];
    const float* rm1 = (const float*)d_in[5];
    const float* rv1 = (const float*)d_in[6];
    const float* W2  = (const float*)d_in[7];
    const float* b2  = (const float*)d_in[8];
    const float* g2  = (const float*)d_in[9];
    const float* be2 = (const float*)d_in[10];
    const float* rm2 = (const float*)d_in[11];
    const float* rv2 = (const float*)d_in[12];
    const float* W3  = (const float*)d_in[13];
    const float* b3  = (const float*)d_in[14];
    const float* g3  = (const float*)d_in[15];
    const float* be3 = (const float*)d_in[16];
    const float* rm3 = (const float*)d_in[17];
    const float* rv3 = (const float*)d_in[18];
    const int* ei    = (const int*)d_in[19];
    const int* batch = (const int*)d_in[20];

    const int N = in_sizes[0] / 3;
    const int E = in_sizes[19] / 2;
    const int G = out_size / 32;
    const int* src = ei;
    const int* dst = ei + E;

    const int B = 256;
    const int nbins = (N + (1 << BINSHIFT) - 1) >> BINSHIFT;          // 196 for N=100k
    const int cap = (((E / nbins) * 3) / 2 + 15) & ~15;               // 1.5x mean
    const int STAGE_BLOCKS = 512;
    const int chunk = (((E + STAGE_BLOCKS - 1) / STAGE_BLOCKS) + 3) & ~3;  // 4-aligned

    // workspace layout
    int*      gcur    = (int*)d_ws;                       // 256*GSTRIDE
    int*      binbase = gcur + 256 * GSTRIDE;             // 256
    int*      cnt     = binbase + 256;                    // N
    float*    dinv    = (float*)(cnt + N);                // N
    int*      rowptr  = (int*)(dinv + N);                 // N
    int*      eidx    = rowptr + N;                       // E
    float4*   xs      = (float4*)(((uintptr_t)(eidx + E) + 15) & ~(uintptr_t)15);  // N
    uint32_t* Tp      = (uint32_t*)(xs + N);              // N*32 (row-major)
    float*    hbuf    = (float*)(Tp + (size_t)N * 32);    // N*64
    float*    gcnt    = hbuf + (size_t)N * 64;            // G
    int2*     staged  = (int2*)hbuf;                      // alias: dead before hbuf written
    float*    out     = (float*)d_out;

    // ---- CSR build: multisplit stage -> bin scan -> per-bin fill ----
    hipMemsetAsync(gcur, 0, 256 * GSTRIDE * 4, stream);
    stage_ms_kernel<<<STAGE_BLOCKS, 256, 0, stream>>>(src, dst, gcur, staged, cap, nbins, E, chunk);
    binscan_kernel<<<1, 256, 0, stream>>>(gcur, binbase, nbins, out, gcnt, G);
    fill_csr_kernel<<<nbins, 256, 0, stream>>>(staged, binbase, gcur, x, cap,
                                               rowptr, cnt, dinv, xs, eidx, N);

    // ---- layer 1 fused: gather + GEMM(3->64) + BN ----
    layer1_kernel<<<(N + 7) / 8, 256, 0, stream>>>(xs, rowptr, cnt, eidx, dinv,
                                                   W1, b1, g1, be1, rm1, rv1, hbuf, N);

    // ---- layer 2 ----
    gemm_pack_scale_kernel<64, 64><<<(N + 31) / 32, 256, 0, stream>>>(hbuf, W2, dinv, Tp, N);
    gather_fuse_kernel<64><<<(int)(((size_t)N * 16 + B - 1) / B), B, 0, stream>>>(
        Tp, rowptr, cnt, eidx, dinv, b2, g2, be2, rm2, rv2, hbuf, N);

    // ---- layer 3 ----
    gemm_pack_scale_kernel<64, 32><<<(N + 63) / 64, 256, 0, stream>>>(hbuf, W3, dinv, Tp, N);
    gather_fuse_kernel<32><<<(int)(((size_t)N * 8 + B - 1) / B), B, 0, stream>>>(
        Tp, rowptr, cnt, eidx, dinv, b3, g3, be3, rm3, rv3, hbuf, N);

    // ---- mean pool ----
    pool_kernel2<<<(N + POOL_ROWS - 1) / POOL_ROWS, 256, 0, stream>>>(hbuf, batch, out, gcnt, N);
    pool_div_kernel<<<(G * 32 + B - 1) / B, B, 0, stream>>>(out, gcnt, G);
}

// Round 16
// 278.926 us; speedup vs baseline: 1.2347x; 1.0131x over previous
//
#include <hip/hip_runtime.h>

#define EPS_BN 1e-5f
#define NEG_SLOPE 0.01f

#define BINSHIFT 9                 // 512 nodes per bin
#define NBINS_LDS 200              // supports N up to 102400
#define BUFCAP 24                  // LDS records per (block,bin)
#define GSTRIDE 16                 // gcur padding: one counter per 64B line

// ---- bf16x2 pack/unpack (RNE) ----
__device__ __forceinline__ uint32_t pack2_bf16(float x, float y) {
    uint32_t ux = __float_as_uint(x);
    uint32_t uy = __float_as_uint(y);
    ux = (ux + 0x7fffu + ((ux >> 16) & 1u)) >> 16;
    uy = (uy + 0x7fffu + ((uy >> 16) & 1u)) >> 16;
    return (uy << 16) | (ux & 0xffffu);
}
__device__ __forceinline__ float bf_lo(uint32_t p) { return __uint_as_float(p << 16); }
__device__ __forceinline__ float bf_hi(uint32_t p) { return __uint_as_float(p & 0xffff0000u); }

// ---- phase A: LDS multisplit; 4 edges/thread/iter; pipelined drain atomics ----
__global__ void __launch_bounds__(256) stage_ms_kernel(
        const int* __restrict__ src, const int* __restrict__ dst,
        int* __restrict__ gcur, int2* __restrict__ staged,
        int cap, int nbins, int E, int chunk) {
    __shared__ int2 bbuf[NBINS_LDS][BUFCAP];
    __shared__ int bcnt[NBINS_LDS];
    __shared__ int gpos[NBINS_LDS];
    for (int i = threadIdx.x; i < nbins; i += 256) bcnt[i] = 0;
    __syncthreads();
    int e0 = blockIdx.x * chunk;
    int e1 = min(e0 + chunk, E);
    for (int base = e0; base < e1; base += 1024) {       // 256 threads x 4 edges
        int e = base + threadIdx.x * 4;
        int s0, s1, s2, s3, d0, d1, d2, d3;
        int ne = 0;
        if (e + 4 <= e1) {
            int4 s4 = *(const int4*)(src + e);
            int4 d4 = *(const int4*)(dst + e);
            s0 = s4.x; s1 = s4.y; s2 = s4.z; s3 = s4.w;
            d0 = d4.x; d1 = d4.y; d2 = d4.z; d3 = d4.w;
            ne = 4;
        } else {
            int k = 0;
            for (; e + k < e1 && k < 4; ++k) {
                int sv = src[e + k], dv = dst[e + k];
                if (k == 0) { s0 = sv; d0 = dv; }
                else if (k == 1) { s1 = sv; d1 = dv; }
                else if (k == 2) { s2 = sv; d2 = dv; }
                else { s3 = sv; d3 = dv; }
            }
            ne = k;
        }
        #pragma unroll
        for (int k = 0; k < 4; ++k) {
            if (k >= ne) break;
            int s = (k == 0) ? s0 : (k == 1) ? s1 : (k == 2) ? s2 : s3;
            int d = (k == 0) ? d0 : (k == 1) ? d1 : (k == 2) ? d2 : d3;
            int bin = d >> BINSHIFT;
            int pos = atomicAdd(&bcnt[bin], 1);
            if (pos < BUFCAP) {
                bbuf[bin][pos] = make_int2(s, d);
            } else {                                     // rare: direct global append
                int gp = atomicAdd(&gcur[bin * GSTRIDE], 1);
                staged[(size_t)bin * cap + gp] = make_int2(s, d);
            }
        }
    }
    __syncthreads();
    // drain phase 1: one bin per THREAD -> all global atomics issue concurrently
    for (int b = threadIdx.x; b < nbins; b += 256) {
        int c = min(bcnt[b], BUFCAP);
        gpos[b] = (c > 0) ? atomicAdd(&gcur[b * GSTRIDE], c) : 0;
    }
    __syncthreads();
    // drain phase 2: cooperative 16-lane copy per bin
    int grp = threadIdx.x >> 4, lane = threadIdx.x & 15;
    for (int b = grp; b < nbins; b += 16) {
        int c = min(bcnt[b], BUFCAP);
        int gp = gpos[b];
        for (int i = lane; i < c; i += 16)
            staged[(size_t)b * cap + gp + i] = bbuf[b][i];
    }
}

// ---- phase B: per-bin CSR fill + rowptr/cnt/dinv/xs. Computes its own
// binbase (LDS reduce of gcur[i<bin], 196 values) -> binscan kernel deleted.
// Block 0 also zeroes out/gcnt.
__global__ void __launch_bounds__(256) fill_csr_kernel(
        const int2* __restrict__ staged, const int* __restrict__ gcur,
        const float* __restrict__ x, int cap, int nbins,
        int* __restrict__ rowptr, int* __restrict__ cnt,
        float* __restrict__ dinv, float4* __restrict__ xs,
        int* __restrict__ eidx, int N,
        float* __restrict__ out, float* __restrict__ gcnt, int G) {
    __shared__ int lcnt[1 << BINSHIFT];
    __shared__ int loff[1 << BINSHIFT];
    __shared__ int ps[256];
    int bin = blockIdx.x;
    // ---- binbase = sum of gcur[i] for i < bin ----
    int v = (threadIdx.x < nbins && threadIdx.x < bin) ? gcur[threadIdx.x * GSTRIDE] : 0;
    ps[threadIdx.x] = v;
    __syncthreads();
    for (int off = 128; off; off >>= 1) {
        if (threadIdx.x < off) ps[threadIdx.x] += ps[threadIdx.x + off];
        __syncthreads();
    }
    int bb = ps[0];
    __syncthreads();
    // ---- block 0: zero pool accumulators (used much later by pool_kernel2) ----
    if (bin == 0) {
        for (int i = threadIdx.x; i < G * 32; i += 256) out[i] = 0.f;
        for (int i = threadIdx.x; i < G; i += 256) gcnt[i] = 0.f;
    }
    int node0 = bin << BINSHIFT;
    int nn = min(1 << BINSHIFT, N - node0);
    int nrec = gcur[bin * GSTRIDE];
    const int2* recs = staged + (size_t)bin * cap;
    for (int i = threadIdx.x; i < (1 << BINSHIFT); i += 256) lcnt[i] = 0;
    __syncthreads();
    for (int t = threadIdx.x; t < nrec; t += 256) atomicAdd(&lcnt[recs[t].y - node0], 1);
    __syncthreads();
    int p0 = lcnt[2 * threadIdx.x], p1 = lcnt[2 * threadIdx.x + 1];
    int pv = p0 + p1;
    ps[threadIdx.x] = pv;
    __syncthreads();
    for (int off = 1; off < 256; off <<= 1) {
        int t = (threadIdx.x >= off) ? ps[threadIdx.x - off] : 0;
        __syncthreads();
        ps[threadIdx.x] += t;
        __syncthreads();
    }
    int base = ps[threadIdx.x] - pv;
    loff[2 * threadIdx.x] = base;
    loff[2 * threadIdx.x + 1] = base + p0;
    __syncthreads();
    for (int i = threadIdx.x; i < nn; i += 256) {
        int node = node0 + i;
        rowptr[node] = bb + loff[i];
        cnt[node] = lcnt[i];
        float di = rsqrtf((float)(lcnt[i] + 1));         // +1 self-loop
        dinv[node] = di;
        const float* xr = x + (size_t)node * 3;
        xs[node] = make_float4(xr[0] * di, xr[1] * di, xr[2] * di, 0.f);
        lcnt[i] = 0;                                     // reuse as cursor
    }
    __syncthreads();
    for (int t = threadIdx.x; t < nrec; t += 256) {
        int2 r = recs[t];
        int li = r.y - node0;
        int p = atomicAdd(&lcnt[li], 1);
        eidx[bb + loff[li] + p] = r.x;                   // block-private range
    }
}

// ---- fused layer 1: gather xs + (3->64 GEMM) + bias + BN + LeakyReLU ----
__global__ void __launch_bounds__(256) layer1_kernel(
        const float4* __restrict__ xs, const int* __restrict__ rowptr,
        const int* __restrict__ cnt, const int* __restrict__ eidx,
        const float* __restrict__ dinv, const float* __restrict__ W,
        const float* __restrict__ b, const float* __restrict__ gamma,
        const float* __restrict__ beta, const float* __restrict__ rm,
        const float* __restrict__ rv, float* __restrict__ h, int N) {
    __shared__ float sW[3 * 64];
    __shared__ float sScale[64], sShift[64];
    if (threadIdx.x < 3 * 64) sW[threadIdx.x] = W[threadIdx.x];
    if (threadIdx.x < 64) {
        int f = threadIdx.x;
        float sc = rsqrtf(rv[f] + EPS_BN) * gamma[f];
        sScale[f] = sc;
        sShift[f] = (b[f] - rm[f]) * sc + beta[f];
    }
    __syncthreads();
    int node = blockIdx.x * 8 + (int)(threadIdx.x >> 5);
    if (node >= N) return;
    int lane = threadIdx.x & 31;
    int start = rowptr[node], deg = cnt[node];
    float ax = 0.f, ay = 0.f, az = 0.f;
    for (int j = lane; j < deg; j += 32) {
        float4 v = xs[eidx[start + j]];
        ax += v.x; ay += v.y; az += v.z;
    }
    for (int o = 16; o; o >>= 1) {
        ax += __shfl_down(ax, o, 32);
        ay += __shfl_down(ay, o, 32);
        az += __shfl_down(az, o, 32);
    }
    ax = __shfl(ax, 0, 32); ay = __shfl(ay, 0, 32); az = __shfl(az, 0, 32);
    float4 self = xs[node];
    float di = dinv[node];
    float gx = (ax + self.x) * di, gy = (ay + self.y) * di, gz = (az + self.z) * di;
    int f0 = lane * 2, f1 = f0 + 1;
    float a0 = gx * sW[f0] + gy * sW[64 + f0] + gz * sW[128 + f0];
    float a1 = gx * sW[f1] + gy * sW[64 + f1] + gz * sW[128 + f1];
    float y0 = a0 * sScale[f0] + sShift[f0];
    float y1 = a1 * sScale[f1] + sShift[f1];
    float2 o2;
    o2.x = (y0 >= 0.f) ? y0 : NEG_SLOPE * y0;
    o2.y = (y1 >= 0.f) ? y1 : NEG_SLOPE * y1;
    *(float2*)(h + (size_t)node * 64 + f0) = o2;
}

// ---- dense GEMM + dinv row-scale + bf16 pack; 4 nodes/thread, row-major Tp.
// #pragma unroll 1: R10/R11 showed full unroll -> ~1 GB scratch spill.
template <int FIN, int FOUT>
__global__ void __launch_bounds__(256, 4) gemm_pack_scale_kernel(
        const float* __restrict__ H, const float* __restrict__ W,
        const float* __restrict__ dinv, uint32_t* __restrict__ Tp, int N) {
    constexpr int TPN = FOUT / 2;          // threads per node-group
    constexpr int NG = 256 / TPN;          // node-groups per block
    constexpr int NPB = NG * 4;            // nodes per block (4 per group)
    __shared__ float sW[FIN * FOUT];
    for (int i = threadIdx.x; i < FIN * FOUT; i += 256) sW[i] = W[i];
    __syncthreads();
    int grp = threadIdx.x / TPN;
    int f2 = threadIdx.x % TPN;
    int n0 = blockIdx.x * NPB + grp;
    int n1 = n0 + NG, n2 = n0 + 2 * NG, n3 = n0 + 3 * NG;
    int m0 = min(n0, N - 1), m1 = min(n1, N - 1), m2 = min(n2, N - 1), m3 = min(n3, N - 1);
    const float* h0 = H + (size_t)m0 * FIN;
    const float* h1 = H + (size_t)m1 * FIN;
    const float* h2 = H + (size_t)m2 * FIN;
    const float* h3 = H + (size_t)m3 * FIN;
    const float2* w2 = (const float2*)sW + f2;
    float a00 = 0.f, a01 = 0.f, a10 = 0.f, a11 = 0.f;
    float a20 = 0.f, a21 = 0.f, a30 = 0.f, a31 = 0.f;
    #pragma unroll 1
    for (int k = 0; k < FIN; k += 4) {
        float4 v0 = *(const float4*)(h0 + k);
        float4 v1 = *(const float4*)(h1 + k);
        float4 v2 = *(const float4*)(h2 + k);
        float4 v3 = *(const float4*)(h3 + k);
        float2 w;
        w = w2[(k + 0) * TPN];
        a00 = fmaf(v0.x, w.x, a00); a01 = fmaf(v0.x, w.y, a01);
        a10 = fmaf(v1.x, w.x, a10); a11 = fmaf(v1.x, w.y, a11);
        a20 = fmaf(v2.x, w.x, a20); a21 = fmaf(v2.x, w.y, a21);
        a30 = fmaf(v3.x, w.x, a30); a31 = fmaf(v3.x, w.y, a31);
        w = w2[(k + 1) * TPN];
        a00 = fmaf(v0.y, w.x, a00); a01 = fmaf(v0.y, w.y, a01);
        a10 = fmaf(v1.y, w.x, a10); a11 = fmaf(v1.y, w.y, a11);
        a20 = fmaf(v2.y, w.x, a20); a21 = fmaf(v2.y, w.y, a21);
        a30 = fmaf(v3.y, w.x, a30); a31 = fmaf(v3.y, w.y, a31);
        w = w2[(k + 2) * TPN];
        a00 = fmaf(v0.z, w.x, a00); a01 = fmaf(v0.z, w.y, a01);
        a10 = fmaf(v1.z, w.x, a10); a11 = fmaf(v1.z, w.y, a11);
        a20 = fmaf(v2.z, w.x, a20); a21 = fmaf(v2.z, w.y, a21);
        a30 = fmaf(v3.z, w.x, a30); a31 = fmaf(v3.z, w.y, a31);
        w = w2[(k + 3) * TPN];
        a00 = fmaf(v0.w, w.x, a00); a01 = fmaf(v0.w, w.y, a01);
        a10 = fmaf(v1.w, w.x, a10); a11 = fmaf(v1.w, w.y, a11);
        a20 = fmaf(v2.w, w.x, a20); a21 = fmaf(v2.w, w.y, a21);
        a30 = fmaf(v3.w, w.x, a30); a31 = fmaf(v3.w, w.y, a31);
    }
    if (n0 < N) { float d = dinv[n0]; Tp[(size_t)n0 * TPN + f2] = pack2_bf16(a00 * d, a01 * d); }
    if (n1 < N) { float d = dinv[n1]; Tp[(size_t)n1 * TPN + f2] = pack2_bf16(a10 * d, a11 * d); }
    if (n2 < N) { float d = dinv[n2]; Tp[(size_t)n2 * TPN + f2] = pack2_bf16(a20 * d, a21 * d); }
    if (n3 < N) { float d = dinv[n3]; Tp[(size_t)n3 * TPN + f2] = pack2_bf16(a30 * d, a31 * d); }
}

// ---- CSR gather + BN + LeakyReLU. uint4 (16B) per thread: halves load
// instructions again vs uint2 at constant line traffic (R14/R15 model:
// lines-per-wave-instruction is the currency). 4-row ILP.
template <int F>
__global__ void __launch_bounds__(256) gather_fuse_kernel(
        const uint32_t* __restrict__ Tp, const int* __restrict__ rowptr,
        const int* __restrict__ cnt, const int* __restrict__ eidx,
        const float* __restrict__ dinv,
        const float* __restrict__ b, const float* __restrict__ gamma,
        const float* __restrict__ beta, const float* __restrict__ rm,
        const float* __restrict__ rv,
        float* __restrict__ h, int N) {
    constexpr int TPN4 = F / 8;            // threads per node (uint4 each)
    int tid = blockIdx.x * blockDim.x + threadIdx.x;
    int node = tid / TPN4;
    if (node >= N) return;
    int fq = tid % TPN4;
    const uint4* T4 = (const uint4*)Tp + fq;             // stride TPN4 per node
    int start = rowptr[node];
    int deg = cnt[node];
    uint4 ts = T4[(size_t)node * TPN4];
    float a0 = bf_lo(ts.x), a1 = bf_hi(ts.x), a2 = bf_lo(ts.y), a3 = bf_hi(ts.y);
    float a4 = bf_lo(ts.z), a5 = bf_hi(ts.z), a6 = bf_lo(ts.w), a7 = bf_hi(ts.w);
    float c0 = 0.f, c1 = 0.f, c2 = 0.f, c3 = 0.f;
    float c4 = 0.f, c5 = 0.f, c6 = 0.f, c7 = 0.f;
    const int* ep = eidx + start;
    int j = 0;
    for (; j + 4 <= deg; j += 4) {
        int s0 = ep[j], s1 = ep[j + 1], s2 = ep[j + 2], s3 = ep[j + 3];
        uint4 t0 = T4[(size_t)s0 * TPN4];
        uint4 t1 = T4[(size_t)s1 * TPN4];
        uint4 t2 = T4[(size_t)s2 * TPN4];
        uint4 t3 = T4[(size_t)s3 * TPN4];
        a0 += bf_lo(t0.x) + bf_lo(t2.x);  a1 += bf_hi(t0.x) + bf_hi(t2.x);
        a2 += bf_lo(t0.y) + bf_lo(t2.y);  a3 += bf_hi(t0.y) + bf_hi(t2.y);
        a4 += bf_lo(t0.z) + bf_lo(t2.z);  a5 += bf_hi(t0.z) + bf_hi(t2.z);
        a6 += bf_lo(t0.w) + bf_lo(t2.w);  a7 += bf_hi(t0.w) + bf_hi(t2.w);
        c0 += bf_lo(t1.x) + bf_lo(t3.x);  c1 += bf_hi(t1.x) + bf_hi(t3.x);
        c2 += bf_lo(t1.y) + bf_lo(t3.y);  c3 += bf_hi(t1.y) + bf_hi(t3.y);
        c4 += bf_lo(t1.z) + bf_lo(t3.z);  c5 += bf_hi(t1.z) + bf_hi(t3.z);
        c6 += bf_lo(t1.w) + bf_lo(t3.w);  c7 += bf_hi(t1.w) + bf_hi(t3.w);
    }
    for (; j < deg; ++j) {
        uint4 t0 = T4[(size_t)ep[j] * TPN4];
        a0 += bf_lo(t0.x); a1 += bf_hi(t0.x);
        a2 += bf_lo(t0.y); a3 += bf_hi(t0.y);
        a4 += bf_lo(t0.z); a5 += bf_hi(t0.z);
        a6 += bf_lo(t0.w); a7 += bf_hi(t0.w);
    }
    float di = dinv[node];
    int f0 = 8 * fq;
    float y[8];
    float av[8] = {a0 + c0, a1 + c1, a2 + c2, a3 + c3,
                   a4 + c4, a5 + c5, a6 + c6, a7 + c7};
    #pragma unroll
    for (int q = 0; q < 8; ++q) {
        float sc = rsqrtf(rv[f0 + q] + EPS_BN) * gamma[f0 + q];
        float yy = av[q] * di * sc + (b[f0 + q] - rm[f0 + q]) * sc + beta[f0 + q];
        y[q] = (yy >= 0.f) ? yy : NEG_SLOPE * yy;
    }
    float* hp = h + (size_t)node * F + f0;
    *(float4*)hp = make_float4(y[0], y[1], y[2], y[3]);
    *(float4*)(hp + 4) = make_float4(y[4], y[5], y[6], y[7]);
}

// ---- mean pool: batch sorted -> register-accumulate, flush on graph change ----
#define POOL_ROWS 128
__global__ void pool_kernel2(const float* __restrict__ h, const int* __restrict__ batch,
                             float* __restrict__ out, float* __restrict__ gcnt, int N) {
    int f = threadIdx.x & 31;
    int rg = threadIdx.x >> 5;
    int n0 = blockIdx.x * POOL_ROWS;
    float acc = 0.f;
    int cnt = 0, gcur = -1;
    for (int r = rg; r < POOL_ROWS; r += 8) {
        int node = n0 + r;
        if (node >= N) break;
        int g = batch[node];
        if (g != gcur) {
            if (gcur >= 0) {
                atomicAdd(&out[(gcur << 5) + f], acc);
                if (f == 0) atomicAdd(&gcnt[gcur], (float)cnt);
            }
            gcur = g; acc = 0.f; cnt = 0;
        }
        acc += h[(size_t)node * 32 + f];
        cnt++;
    }
    if (gcur >= 0) {
        atomicAdd(&out[(gcur << 5) + f], acc);
        if (f == 0) atomicAdd(&gcnt[gcur], (float)cnt);
    }
}

__global__ void pool_div_kernel(float* __restrict__ out, const float* __restrict__ gcnt, int G) {
    int tid = blockIdx.x * blockDim.x + threadIdx.x;
    if (tid < (G << 5)) out[tid] /= fmaxf(gcnt[tid >> 5], 1.0f);
}

extern "C" void kernel_launch(void* const* d_in, const int* in_sizes, int n_in,
                              void* d_out, int out_size, void* d_ws, size_t ws_size,
                              hipStream_t stream) {
    const float* x   = (const float*)d_in[0];
    const float* W1  = (const float*)d_in[1];
    const float* b1  = (const float*)d_in[2];
    const float* g1  = (const float*)d_in[3];
    const float* be1 = (const float*)d_in[4];
    const float* rm1 = (const float*)d_in[5];
    const float* rv1 = (const float*)d_in[6];
    const float* W2  = (const float*)d_in[7];
    const float* b2  = (const float*)d_in[8];
    const float* g2  = (const float*)d_in[9];
    const float* be2 = (const float*)d_in[10];
    const float* rm2 = (const float*)d_in[11];
    const float* rv2 = (const float*)d_in[12];
    const float* W3  = (const float*)d_in[13];
    const float* b3  = (const float*)d_in[14];
    const float* g3  = (const float*)d_in[15];
    const float* be3 = (const float*)d_in[16];
    const float* rm3 = (const float*)d_in[17];
    const float* rv3 = (const float*)d_in[18];
    const int* ei    = (const int*)d_in[19];
    const int* batch = (const int*)d_in[20];

    const int N = in_sizes[0] / 3;
    const int E = in_sizes[19] / 2;
    const int G = out_size / 32;
    const int* src = ei;
    const int* dst = ei + E;

    const int B = 256;
    const int nbins = (N + (1 << BINSHIFT) - 1) >> BINSHIFT;          // 196 for N=100k
    const int cap = (((E / nbins) * 3) / 2 + 15) & ~15;               // 1.5x mean
    const int STAGE_BLOCKS = 512;
    const int chunk = (((E + STAGE_BLOCKS - 1) / STAGE_BLOCKS) + 3) & ~3;  // 4-aligned

    // workspace layout
    int*      gcur    = (int*)d_ws;                       // 256*GSTRIDE
    int*      cnt     = gcur + 256 * GSTRIDE;             // N
    float*    dinv    = (float*)(cnt + N);                // N
    int*      rowptr  = (int*)(dinv + N);                 // N
    int*      eidx    = rowptr + N;                       // E
    float4*   xs      = (float4*)(((uintptr_t)(eidx + E) + 15) & ~(uintptr_t)15);  // N
    uint32_t* Tp      = (uint32_t*)(xs + N);              // N*32 (row-major)
    float*    hbuf    = (float*)(Tp + (size_t)N * 32);    // N*64
    float*    gcnt    = hbuf + (size_t)N * 64;            // G
    int2*     staged  = (int2*)hbuf;                      // alias: dead before hbuf written
    float*    out     = (float*)d_out;

    // ---- CSR build: multisplit stage -> per-bin fill (binbase computed in-kernel) ----
    hipMemsetAsync(gcur, 0, 256 * GSTRIDE * 4, stream);
    stage_ms_kernel<<<STAGE_BLOCKS, 256, 0, stream>>>(src, dst, gcur, staged, cap, nbins, E, chunk);
    fill_csr_kernel<<<nbins, 256, 0, stream>>>(staged, gcur, x, cap, nbins,
                                               rowptr, cnt, dinv, xs, eidx, N, out, gcnt, G);

    // ---- layer 1 fused: gather + GEMM(3->64) + BN ----
    layer1_kernel<<<(N + 7) / 8, 256, 0, stream>>>(xs, rowptr, cnt, eidx, dinv,
                                                   W1, b1, g1, be1, rm1, rv1, hbuf, N);

    // ---- layer 2 ----
    gemm_pack_scale_kernel<64, 64><<<(N + 31) / 32, 256, 0, stream>>>(hbuf, W2, dinv, Tp, N);
    gather_fuse_kernel<64><<<(int)(((size_t)N * 8 + B - 1) / B), B, 0, stream>>>(
        Tp, rowptr, cnt, eidx, dinv, b2, g2, be2, rm2, rv2, hbuf, N);

    // ---- layer 3 ----
    gemm_pack_scale_kernel<64, 32><<<(N + 63) / 64, 256, 0, stream>>>(hbuf, W3, dinv, Tp, N);
    gather_fuse_kernel<32><<<(int)(((size_t)N * 4 + B - 1) / B), B, 0, stream>>>(
        Tp, rowptr, cnt, eidx, dinv, b3, g3, be3, rm3, rv3, hbuf, N);

    // ---- mean pool ----
    pool_kernel2<<<(N + POOL_ROWS - 1) / POOL_ROWS, 256, 0, stream>>>(hbuf, batch, out, gcnt, N);
    pool_div_kernel<<<(G * 32 + B - 1) / B, B, 0, stream>>>(out, gcnt, G);
}